// Round 2
// baseline (14763.939 us; speedup 1.0000x reference)
//
#include <hip/hip_runtime.h>
#include <math.h>

namespace {

constexpr int B = 256, T = 64, ACTN = 6, EMB = 1024;
constexpr int S = 32, DD = 32, SFN = 1024;   // stoch groups, classes, flat
constexpr int DET = 600, HID = 600;
constexpr int OUTF = 4 * SFN + DET;          // 4696

__device__ __forceinline__ float elu1(float x) { return x > 0.f ? x : expm1f(x); }
__device__ __forceinline__ float sigm(float x) { return 1.f / (1.f + expf(-x)); }

// ---------------- weight prep ----------------
// WBg[g][j][k] : g in {z,r,h}, j<600, k<1200 (k<600 from Wx row k, else Wh row k-600)
__global__ void kWB(const float* __restrict__ Wx, const float* __restrict__ Wh,
                    float* __restrict__ WBg) {
    int k = blockIdx.x;  // 0..1199
    const float* src = (k < 600) ? (Wx + (size_t)k * 1800) : (Wh + (size_t)(k - 600) * 1800);
    for (int i = threadIdx.x; i < 1800; i += blockDim.x) {
        int g = i / 600, j = i % 600;
        WBg[(size_t)g * 720000 + (size_t)j * 1200 + k] = src[i];
    }
}

// WC[j][k] : j<600 -> W_img2[k][j] ; j>=600 -> W_obs1[k][j-600] (deter rows 0..599)
__global__ void kWC(const float* __restrict__ W2, const float* __restrict__ Wo1,
                    float* __restrict__ WCm) {
    int k = blockIdx.x;  // 0..599
    for (int j = threadIdx.x; j < 1200; j += blockDim.x) {
        float v = (j < 600) ? W2[(size_t)k * 600 + j] : Wo1[(size_t)k * 600 + (j - 600)];
        WCm[(size_t)j * 600 + k] = v;
    }
}

// WD[j][k] : j<1024 -> W_img5[k][j] ; else W_obs3[k][j-1024]
__global__ void kWD(const float* __restrict__ W5, const float* __restrict__ Wo3,
                    float* __restrict__ WDm) {
    int k = blockIdx.x;  // 0..599
    for (int j = threadIdx.x; j < 2048; j += blockDim.x) {
        float v = (j < 1024) ? W5[(size_t)k * 1024 + j] : Wo3[(size_t)k * 1024 + (j - 1024)];
        WDm[(size_t)j * 600 + k] = v;
    }
}

// ---------------- embed precompute: embPre[t][j][b] = b_obs1[j] + sum_k e[b,t,k]*Wo1[600+k][j]
__global__ __launch_bounds__(512) void kPemb(const float* __restrict__ embed,
                                             const float* __restrict__ Wo1,
                                             const float* __restrict__ bo1,
                                             float* __restrict__ embPre) {
    int bid = blockIdx.x;  // t*40 + bg*10 + jg
    int jg = bid % 10;
    int r = bid / 10;
    int bg = r & 3;
    int t = r >> 2;
    int tid = threadIdx.x;
    int lane = tid & 63;
    int wid = __builtin_amdgcn_readfirstlane(tid >> 6);
    int b0 = bg * 64;
    int j0 = jg * 64 + wid * 8;
    bool active = (j0 < 600);
    __shared__ float tile[64 * 129];
    float acc[8] = {0, 0, 0, 0, 0, 0, 0, 0};
    for (int kc = 0; kc < EMB; kc += 128) {
        __syncthreads();
        for (int ii = tid; ii < 64 * 128; ii += 512) {
            int i = ii >> 7, k = ii & 127;
            tile[i * 129 + k] = embed[((size_t)(b0 + i) * T + t) * EMB + kc + k];
        }
        __syncthreads();
        if (active) {
            const float* wbase = Wo1 + (size_t)(600 + kc) * 600 + j0;
#pragma unroll 4
            for (int k = 0; k < 128; ++k) {
                float v = tile[lane * 129 + k];
                float4 wa = *(const float4*)(wbase + (size_t)k * 600);
                float4 wb = *(const float4*)(wbase + (size_t)k * 600 + 4);
                acc[0] += v * wa.x; acc[1] += v * wa.y; acc[2] += v * wa.z; acc[3] += v * wa.w;
                acc[4] += v * wb.x; acc[5] += v * wb.y; acc[6] += v * wb.z; acc[7] += v * wb.w;
            }
        }
    }
    if (active) {
#pragma unroll
        for (int c = 0; c < 8; ++c)
            embPre[((size_t)t * 600 + j0 + c) * B + b0 + lane] = acc[c] + bo1[j0 + c];
    }
}

// ---------------- stage A: xT[h][b] = elu(b1 + action part + one-hot gather-sum)
__global__ __launch_bounds__(256) void kA(const float* __restrict__ act,
                                          const float* __restrict__ W1,
                                          const float* __restrict__ b1,
                                          const int* __restrict__ idxB,
                                          float* __restrict__ xT, int t, int first) {
    int b = blockIdx.x, tid = threadIdx.x;
    __shared__ float sa[ACTN];
    __shared__ int si[S];
    if (tid < ACTN) sa[tid] = act[((size_t)b * T + t) * ACTN + tid];
    if (!first && tid < S) si[tid] = idxB[b * S + tid];
    __syncthreads();
    for (int h = tid; h < HID; h += 256) {
        float a = b1[h];
#pragma unroll
        for (int k = 0; k < ACTN; ++k) a += sa[k] * W1[(size_t)(SFN + k) * HID + h];
        if (!first) {
#pragma unroll 8
            for (int s = 0; s < S; ++s) a += W1[(size_t)(s * DD + si[s]) * HID + h];
        }
        xT[(size_t)h * B + b] = elu1(a);
    }
}

// ---------------- stage B: fused GRU. Wave = 16 b x 4 jl, 2 j per lane (8 j/wave).
__global__ __launch_bounds__(256) void kB(const float* __restrict__ xT,
                                          const float* __restrict__ dPrev,
                                          const float* __restrict__ WBg,
                                          const float* __restrict__ b_in,
                                          const float* __restrict__ b_rec,
                                          float* __restrict__ dNext,
                                          float* __restrict__ out, int t) {
    int tid = threadIdx.x, lane = tid & 63, wv = tid >> 6;
    int bl = lane & 15, jl = lane >> 4;
    int jg = blockIdx.x >> 2;              // 0..74
    int bg = (blockIdx.x & 3) * 4 + wv;    // 0..15
    int b = bg * 16 + bl;
    int j0 = jg * 8 + jl;                  // lane's j's: j0, j0+4
    const float* wz = WBg + (size_t)j0 * 1200;
    const float* wr = wz + 720000;
    const float* wc = wz + 1440000;
    const float* xa = xT + b;
    const float* da = dPrev + b;
    float az0 = 0, ar0 = 0, ax0 = 0, ah0 = 0;
    float az1 = 0, ar1 = 0, ax1 = 0, ah1 = 0;
#pragma unroll 2
    for (int k = 0; k < 600; k += 4) {
        float x0 = xa[(size_t)(k + 0) * B];
        float x1 = xa[(size_t)(k + 1) * B];
        float x2 = xa[(size_t)(k + 2) * B];
        float x3 = xa[(size_t)(k + 3) * B];
        float4 z0 = *(const float4*)(wz + k), z1 = *(const float4*)(wz + 4800 + k);
        float4 r0 = *(const float4*)(wr + k), r1 = *(const float4*)(wr + 4800 + k);
        float4 c0 = *(const float4*)(wc + k), c1 = *(const float4*)(wc + 4800 + k);
        az0 += x0 * z0.x + x1 * z0.y + x2 * z0.z + x3 * z0.w;
        az1 += x0 * z1.x + x1 * z1.y + x2 * z1.z + x3 * z1.w;
        ar0 += x0 * r0.x + x1 * r0.y + x2 * r0.z + x3 * r0.w;
        ar1 += x0 * r1.x + x1 * r1.y + x2 * r1.z + x3 * r1.w;
        ax0 += x0 * c0.x + x1 * c0.y + x2 * c0.z + x3 * c0.w;
        ax1 += x0 * c1.x + x1 * c1.y + x2 * c1.z + x3 * c1.w;
    }
#pragma unroll 2
    for (int k = 0; k < 600; k += 4) {
        float x0 = da[(size_t)(k + 0) * B];
        float x1 = da[(size_t)(k + 1) * B];
        float x2 = da[(size_t)(k + 2) * B];
        float x3 = da[(size_t)(k + 3) * B];
        float4 z0 = *(const float4*)(wz + 600 + k), z1 = *(const float4*)(wz + 5400 + k);
        float4 r0 = *(const float4*)(wr + 600 + k), r1 = *(const float4*)(wr + 5400 + k);
        float4 c0 = *(const float4*)(wc + 600 + k), c1 = *(const float4*)(wc + 5400 + k);
        az0 += x0 * z0.x + x1 * z0.y + x2 * z0.z + x3 * z0.w;
        az1 += x0 * z1.x + x1 * z1.y + x2 * z1.z + x3 * z1.w;
        ar0 += x0 * r0.x + x1 * r0.y + x2 * r0.z + x3 * r0.w;
        ar1 += x0 * r1.x + x1 * r1.y + x2 * r1.z + x3 * r1.w;
        ah0 += x0 * c0.x + x1 * c0.y + x2 * c0.z + x3 * c0.w;
        ah1 += x0 * c1.x + x1 * c1.y + x2 * c1.z + x3 * c1.w;
    }
    size_t ob = ((size_t)b * T + t) * OUTF + 2 * SFN;
    {
        int j = j0;
        float dp = dPrev[(size_t)j * B + b];
        float z = sigm(az0 + b_in[j] + b_rec[j]);
        float rr = sigm(ar0 + b_in[600 + j] + b_rec[600 + j]);
        float cd = tanhf(ax0 + b_in[1200 + j] + rr * (ah0 + b_rec[1200 + j]));
        float dn = z * dp + (1.f - z) * cd;
        dNext[(size_t)j * B + b] = dn;
        out[ob + j] = dn;
    }
    {
        int j = j0 + 4;
        float dp = dPrev[(size_t)j * B + b];
        float z = sigm(az1 + b_in[j] + b_rec[j]);
        float rr = sigm(ar1 + b_in[600 + j] + b_rec[600 + j]);
        float cd = tanhf(ax1 + b_in[1200 + j] + rr * (ah1 + b_rec[1200 + j]));
        float dn = z * dp + (1.f - z) * cd;
        dNext[(size_t)j * B + b] = dn;
        out[ob + j] = dn;
    }
}

// ---------------- stage C: wave = 16 b x 4 jl, 2 j per lane (8 j/wave).
__global__ __launch_bounds__(256) void kC(const float* __restrict__ dT,
                                          const float* __restrict__ WCm,
                                          const float* __restrict__ b2,
                                          const float* __restrict__ embPre,
                                          float* __restrict__ yoT, int t) {
    int tid = threadIdx.x, lane = tid & 63, wv = tid >> 6;
    int bl = lane & 15, jl = lane >> 4;
    int jg = blockIdx.x >> 2;              // 0..149
    int bg = (blockIdx.x & 3) * 4 + wv;    // 0..15
    int b = bg * 16 + bl;
    int j0 = jg * 8 + jl;
    const float* w0 = WCm + (size_t)j0 * 600;
    const float* w1 = w0 + 2400;
    const float* da = dT + b;
    float a0 = 0, a1 = 0;
#pragma unroll 2
    for (int k = 0; k < 600; k += 4) {
        float x0 = da[(size_t)(k + 0) * B];
        float x1 = da[(size_t)(k + 1) * B];
        float x2 = da[(size_t)(k + 2) * B];
        float x3 = da[(size_t)(k + 3) * B];
        float4 p = *(const float4*)(w0 + k);
        float4 q = *(const float4*)(w1 + k);
        a0 += x0 * p.x + x1 * p.y + x2 * p.z + x3 * p.w;
        a1 += x0 * q.x + x1 * q.y + x2 * q.z + x3 * q.w;
    }
#pragma unroll
    for (int ja = 0; ja < 2; ++ja) {
        int j = j0 + 4 * ja;
        float a = ja ? a1 : a0;
        float v = (j < 600) ? elu1(a + b2[j])
                            : elu1(a + embPre[((size_t)t * 600 + (j - 600)) * B + b]);
        yoT[(size_t)j * B + b] = v;
    }
}

// ---------------- stage D: wave = 16 b x 4 jl, 8 j per lane -> full 32-class group per wave.
__global__ __launch_bounds__(128) void kD(const float* __restrict__ yoT,
                                          const float* __restrict__ WDm,
                                          const float* __restrict__ b5,
                                          const float* __restrict__ bo3,
                                          const float* __restrict__ gImg,
                                          const float* __restrict__ gObs,
                                          float* __restrict__ out,
                                          int* __restrict__ idxB, int t) {
    int tid = threadIdx.x, lane = tid & 63, wv = tid >> 6;
    int bl = lane & 15, jl = lane >> 4;
    int sg = blockIdx.x >> 3;              // 0..63
    int bg = (blockIdx.x & 7) * 2 + wv;    // 0..15
    int post = (sg >= 32) ? 1 : 0;
    int s = post ? sg - 32 : sg;
    int b = bg * 16 + bl;
    const float* src = yoT + (post ? (size_t)600 * B : 0) + b;
    const float* w = WDm + ((size_t)(post * SFN) + s * DD + jl) * 600;
    float acc[8] = {0, 0, 0, 0, 0, 0, 0, 0};
#pragma unroll 2
    for (int k = 0; k < 600; k += 4) {
        float x0 = src[(size_t)(k + 0) * B];
        float x1 = src[(size_t)(k + 1) * B];
        float x2 = src[(size_t)(k + 2) * B];
        float x3 = src[(size_t)(k + 3) * B];
#pragma unroll
        for (int ja = 0; ja < 8; ++ja) {
            float4 p = *(const float4*)(w + (size_t)ja * 2400 + k);
            acc[ja] += x0 * p.x + x1 * p.y + x2 * p.z + x3 * p.w;
        }
    }
    const float* bias = (post ? bo3 : b5) + s * DD + jl;
    const float* g = (post ? gObs : gImg) + ((size_t)b * T + t) * SFN + s * DD + jl;
    size_t obase = ((size_t)b * T + t) * OUTF;
    size_t lbase = obase + (post ? 0 : 2 * SFN + DET) + s * DD + jl;
    size_t sbase = obase + (post ? SFN : 3 * SFN + DET) + s * DD + jl;
    float bm = -INFINITY;
    int bi = 0;
#pragma unroll
    for (int ja = 0; ja < 8; ++ja) {
        float lg = acc[ja] + bias[ja * 4];
        out[lbase + ja * 4] = lg;
        float v = lg + g[ja * 4];
        if (v > bm) { bm = v; bi = ja * 4 + jl; }
    }
    // reduce across the 4 jl groups (lanes differing in bits 4,5)
    for (int m = 16; m < 64; m <<= 1) {
        float ov = __shfl_xor(bm, m, 64);
        int oi = __shfl_xor(bi, m, 64);
        if (ov > bm || (ov == bm && oi < bi)) { bm = ov; bi = oi; }
    }
#pragma unroll
    for (int ja = 0; ja < 8; ++ja)
        out[sbase + ja * 4] = (ja * 4 + jl == bi) ? 1.f : 0.f;
    if (post && jl == 0) idxB[b * S + s] = bi;
}

}  // namespace

extern "C" void kernel_launch(void* const* d_in, const int* in_sizes, int n_in,
                              void* d_out, int out_size, void* d_ws, size_t ws_size,
                              hipStream_t stream) {
    const float* action = (const float*)d_in[0];
    const float* embed  = (const float*)d_in[1];
    const float* gImg   = (const float*)d_in[2];
    const float* gObs   = (const float*)d_in[3];
    const float* W1     = (const float*)d_in[4];
    const float* b1     = (const float*)d_in[5];
    const float* Wx     = (const float*)d_in[6];
    const float* Wh     = (const float*)d_in[7];
    const float* b_in   = (const float*)d_in[8];
    const float* b_rec  = (const float*)d_in[9];
    const float* W2     = (const float*)d_in[10];
    const float* b2     = (const float*)d_in[11];
    const float* W5     = (const float*)d_in[12];
    const float* b5     = (const float*)d_in[13];
    const float* Wo1    = (const float*)d_in[14];
    const float* bo1    = (const float*)d_in[15];
    const float* Wo3    = (const float*)d_in[16];
    const float* bo3    = (const float*)d_in[17];
    float* out = (float*)d_out;

    float* ws = (float*)d_ws;
    float* WBg    = ws;                  // 3*600*1200 = 2,160,000 f
    float* WCm    = WBg + 2160000;       // 1200*600   =   720,000 f
    float* WDm    = WCm + 720000;        // 2048*600   = 1,228,800 f
    float* embPre = WDm + 1228800;       // 64*600*256 = 9,830,400 f
    float* xT     = embPre + 9830400;    // 600*256
    float* dA     = xT + 153600;
    float* dB     = dA + 153600;
    float* yoT    = dB + 153600;         // 1200*256
    int*   idxB   = (int*)(yoT + 307200);

    hipMemsetAsync(dA, 0, 153600 * sizeof(float), stream);  // deter0 = zeros
    kWB<<<1200, 256, 0, stream>>>(Wx, Wh, WBg);
    kWC<<<600, 256, 0, stream>>>(W2, Wo1, WCm);
    kWD<<<600, 256, 0, stream>>>(W5, Wo3, WDm);
    kPemb<<<2560, 512, 0, stream>>>(embed, Wo1, bo1, embPre);

    for (int t = 0; t < T; ++t) {
        float* dP = (t & 1) ? dB : dA;
        float* dN = (t & 1) ? dA : dB;
        kA<<<256, 256, 0, stream>>>(action, W1, b1, idxB, xT, t, t == 0 ? 1 : 0);
        kB<<<300, 256, 0, stream>>>(xT, dP, WBg, b_in, b_rec, dN, out, t);
        kC<<<600, 256, 0, stream>>>(dN, WCm, b2, embPre, yoT, t);
        kD<<<512, 128, 0, stream>>>(yoT, WDm, b5, bo3, gImg, gObs, out, idxB, t);
    }
}